// Round 8
// baseline (11210.921 us; speedup 1.0000x reference)
//
#include <hip/hip_runtime.h>

#define T_N 4096
#define B_N 64
#define I_N 128
#define H_N 128
#define BH  (B_N * H_N)

// ---------------------------------------------------------------------------
// Phase 1: xp = x @ W_ih^T + b_ih -> into out (in-place with phase 2).
// Unchanged from R2-R7 (~70 us).
// ---------------------------------------------------------------------------
__global__ __launch_bounds__(256) void xproj_kernel(
    const float* __restrict__ x, const float* __restrict__ Wih,
    const float* __restrict__ bih, float* __restrict__ xp)
{
    __shared__ float wt[I_N][H_N];   // wt[k][j] = Wih[j][k], 64 KB
    const int tid = threadIdx.x;

    {
        const float4* w4 = (const float4*)Wih;
        #pragma unroll
        for (int it = 0; it < 16; ++it) {
            int i = tid * 16 + it;          // 0..4095 float4s
            float4 v = w4[i];
            int r = i >> 5;                 // W row j
            int k = (i & 31) << 2;          // k base
            wt[k + 0][r] = v.x;
            wt[k + 1][r] = v.y;
            wt[k + 2][r] = v.z;
            wt[k + 3][r] = v.w;
        }
    }
    __syncthreads();

    const int  tx   = tid & 15;
    const int  ty   = tid >> 4;
    const long row0 = (long)blockIdx.x * 128;
    const float* xbase = x + (row0 + ty * 8) * I_N;

    float acc[8][8];
    #pragma unroll
    for (int r = 0; r < 8; ++r)
        #pragma unroll
        for (int c = 0; c < 8; ++c) acc[r][c] = 0.0f;

    #pragma unroll 2
    for (int k4 = 0; k4 < I_N / 4; ++k4) {
        float4 xv[8];
        #pragma unroll
        for (int r = 0; r < 8; ++r)
            xv[r] = *(const float4*)(xbase + r * I_N + k4 * 4);

        #pragma unroll
        for (int kk = 0; kk < 4; ++kk) {
            int k = k4 * 4 + kk;
            float4 w0 = *(const float4*)&wt[k][tx * 4];
            float4 w1 = *(const float4*)&wt[k][64 + tx * 4];
            #pragma unroll
            for (int r = 0; r < 8; ++r) {
                float xk = (kk == 0) ? xv[r].x : (kk == 1) ? xv[r].y
                         : (kk == 2) ? xv[r].z : xv[r].w;
                acc[r][0] = fmaf(xk, w0.x, acc[r][0]);
                acc[r][1] = fmaf(xk, w0.y, acc[r][1]);
                acc[r][2] = fmaf(xk, w0.z, acc[r][2]);
                acc[r][3] = fmaf(xk, w0.w, acc[r][3]);
                acc[r][4] = fmaf(xk, w1.x, acc[r][4]);
                acc[r][5] = fmaf(xk, w1.y, acc[r][5]);
                acc[r][6] = fmaf(xk, w1.z, acc[r][6]);
                acc[r][7] = fmaf(xk, w1.w, acc[r][7]);
            }
        }
    }

    float4 b0 = *(const float4*)(bih + tx * 4);
    float4 b1 = *(const float4*)(bih + 64 + tx * 4);
    #pragma unroll
    for (int r = 0; r < 8; ++r) {
        long row = row0 + ty * 8 + r;
        float4 o0, o1;
        o0.x = acc[r][0] + b0.x;  o0.y = acc[r][1] + b0.y;
        o0.z = acc[r][2] + b0.z;  o0.w = acc[r][3] + b0.w;
        o1.x = acc[r][4] + b1.x;  o1.y = acc[r][5] + b1.y;
        o1.z = acc[r][6] + b1.z;  o1.w = acc[r][7] + b1.w;
        *(float4*)(xp + row * H_N + tx * 4)      = o0;
        *(float4*)(xp + row * H_N + 64 + tx * 4) = o1;
    }
}

// ---------------------------------------------------------------------------
// Phase 2: scan — EXACTLY the R6 kernel, FROZEN (trusted 1905 us).
// ---------------------------------------------------------------------------
__device__ __forceinline__ float tanh_pade(float x) {
    float u = x * x;
    float n = fmaf(u, u + 105.0f, 945.0f);
    float d = fmaf(u, fmaf(15.0f, u, 420.0f), 945.0f);
    float t = x * n * __builtin_amdgcn_rcpf(d);
    return fminf(1.0f, fmaxf(-1.0f, t));
}

#define ROR1 0x121
#define ROR2 0x122
#define ROR4 0x124
#define ROR8 0x128

__device__ __forceinline__ float ror_add(float v, const int ctrl) {
    int s = __float_as_int(v);
    int r;
    switch (ctrl) {
        case ROR1: r = __builtin_amdgcn_update_dpp(0, s, ROR1, 0xF, 0xF, true); break;
        case ROR2: r = __builtin_amdgcn_update_dpp(0, s, ROR2, 0xF, 0xF, true); break;
        case ROR4: r = __builtin_amdgcn_update_dpp(0, s, ROR4, 0xF, 0xF, true); break;
        default:   r = __builtin_amdgcn_update_dpp(0, s, ROR8, 0xF, 0xF, true); break;
    }
    return v + __int_as_float(r);
}

#define DOT4(W4, H4)                                                          \
    fmaf((W4).x, (H4).x, fmaf((W4).y, (H4).y,                                 \
    fmaf((W4).z, (H4).z, (W4).w * (H4).w)))

__global__ __launch_bounds__(512, 1) void scan_kernel(
    const float* __restrict__ Whh, const float* __restrict__ bhh,
    const float* __restrict__ h0, float* __restrict__ out)
{
    const int tid  = threadIdx.x;
    const int b    = blockIdx.x;
    const int lane = tid & 63;
    const int wv   = tid >> 6;
    const int p    = lane & 15;
    const int jg   = (lane >> 4) + 4 * wv;
    __shared__ float hbuf[2][16][12];

    float4 w4[4][2];
    #pragma unroll
    for (int j = 0; j < 4; ++j)
        #pragma unroll
        for (int c = 0; c < 2; ++c)
            w4[j][c] = *(const float4*)(Whh + (4 * jg + j) * H_N + 8 * p + 4 * c);

    const float4 bh4 = *(const float4*)(bhh + 4 * jg);

    if (tid < H_N) hbuf[0][tid >> 3][tid & 7] = h0[b * H_N + tid];

    const float* xq = out + b * H_N + 4 * jg;
    float*       oq = out + b * H_N + 4 * jg;

    float4 xv[4];
    #pragma unroll
    for (int d = 0; d < 4; ++d)
        xv[d] = *(const float4*)(xq + (size_t)d * BH);

    __syncthreads();

#define RNN_STEP(T0, D, CUR) do {                                             \
        float4 hv0 = *(const float4*)&hbuf[CUR][p][0];                        \
        float4 hv1 = *(const float4*)&hbuf[CUR][p][4];                        \
        float s0 = DOT4(w4[0][0], hv0) + DOT4(w4[0][1], hv1);                 \
        float s1 = DOT4(w4[1][0], hv0) + DOT4(w4[1][1], hv1);                 \
        float s2 = DOT4(w4[2][0], hv0) + DOT4(w4[2][1], hv1);                 \
        float s3 = DOT4(w4[3][0], hv0) + DOT4(w4[3][1], hv1);                 \
        s0 = ror_add(s0, ROR1); s1 = ror_add(s1, ROR1);                       \
        s2 = ror_add(s2, ROR1); s3 = ror_add(s3, ROR1);                       \
        s0 = ror_add(s0, ROR2); s1 = ror_add(s1, ROR2);                       \
        s2 = ror_add(s2, ROR2); s3 = ror_add(s3, ROR2);                       \
        s0 = ror_add(s0, ROR4); s1 = ror_add(s1, ROR4);                       \
        s2 = ror_add(s2, ROR4); s3 = ror_add(s3, ROR4);                       \
        s0 = ror_add(s0, ROR8); s1 = ror_add(s1, ROR8);                       \
        s2 = ror_add(s2, ROR8); s3 = ror_add(s3, ROR8);                       \
        float4 h4;                                                            \
        h4.x = tanh_pade(s0 + xv[D].x + bh4.x);                               \
        h4.y = tanh_pade(s1 + xv[D].y + bh4.y);                               \
        h4.z = tanh_pade(s2 + xv[D].z + bh4.z);                               \
        h4.w = tanh_pade(s3 + xv[D].w + bh4.w);                               \
        if (p == 0)                                                           \
            *(float4*)&hbuf[(CUR) ^ 1][jg >> 1][(jg & 1) << 2] = h4;          \
        if ((T0) + 4 < T_N)                                                   \
            xv[D] = *(const float4*)(xq + (size_t)((T0) + 4) * BH);           \
        if (p == 0) {                                                         \
            *(float4*)(oq + (size_t)(T0) * BH) = h4;                          \
            if ((T0) == T_N - 1) *(float4*)(oq + (size_t)T_N * BH) = h4;      \
        }                                                                     \
        asm volatile("s_waitcnt lgkmcnt(0)" ::: "memory");                    \
        __builtin_amdgcn_s_barrier();                                         \
        asm volatile("" ::: "memory");                                        \
    } while (0)

    for (int t = 0; t < T_N; t += 4) {
        RNN_STEP(t + 0, 0, 0);
        RNN_STEP(t + 1, 1, 1);
        RNN_STEP(t + 2, 2, 0);
        RNN_STEP(t + 3, 3, 1);
    }
#undef RNN_STEP
}

// ---------------------------------------------------------------------------
// P0 x16: CLOCK METER. 65536 x 64 dependent v_fma_f32 = 16.78 Mcyc exactly
// (no memory/LDS/barrier). Sized to be the SLOWEST kernel so it owns the
// top-5 table: dur 6990 us <=> 2.4 GHz; 10486 <=> 1.6 GHz; 13981 <=> 1.2.
// ---------------------------------------------------------------------------
__global__ __launch_bounds__(512, 1) void probe_clock(float* ws) {
    float a = 1.0f + (float)threadIdx.x * 1e-7f;
    const float b = 0.99990f, c = 1e-9f;
    for (int t = 0; t < T_N * 16; ++t) {
        #pragma unroll
        for (int i = 0; i < 64; ++i) a = fmaf(a, b, c);
    }
    if (threadIdx.x == 0) ws[blockIdx.x] = a;
}

// ---------------------------------------------------------------------------
// P3: full scan step (ds_read + DOT4 + DPP + tanh + ds_write + lgkm +
// barrier) with NO global traffic in the loop. Deduced from residual:
// P3 = total - xproj(70) - scan(1905) - P0(table). scan - P3 = global path.
// ---------------------------------------------------------------------------
__global__ __launch_bounds__(512, 1) void probe_novmem(
    const float* __restrict__ Whh, const float* __restrict__ bhh,
    const float* __restrict__ h0, float* ws)
{
    const int tid  = threadIdx.x;
    const int b    = blockIdx.x;
    const int lane = tid & 63;
    const int wv   = tid >> 6;
    const int p    = lane & 15;
    const int jg   = (lane >> 4) + 4 * wv;
    __shared__ float hbuf[2][16][12];

    float4 w4[4][2];
    #pragma unroll
    for (int j = 0; j < 4; ++j)
        #pragma unroll
        for (int c = 0; c < 2; ++c)
            w4[j][c] = *(const float4*)(Whh + (4 * jg + j) * H_N + 8 * p + 4 * c);

    const float4 bh4 = *(const float4*)(bhh + 4 * jg);
    const float4 xvf = *(const float4*)(h0 + ((b * H_N + 4 * jg) & (H_N * B_N - 4)));

    if (tid < H_N) hbuf[0][tid >> 3][tid & 7] = h0[b * H_N + tid];
    __syncthreads();

#define PSTEP(CUR) do {                                                       \
        float4 hv0 = *(const float4*)&hbuf[CUR][p][0];                        \
        float4 hv1 = *(const float4*)&hbuf[CUR][p][4];                        \
        float s0 = DOT4(w4[0][0], hv0) + DOT4(w4[0][1], hv1);                 \
        float s1 = DOT4(w4[1][0], hv0) + DOT4(w4[1][1], hv1);                 \
        float s2 = DOT4(w4[2][0], hv0) + DOT4(w4[2][1], hv1);                 \
        float s3 = DOT4(w4[3][0], hv0) + DOT4(w4[3][1], hv1);                 \
        s0 = ror_add(s0, ROR1); s1 = ror_add(s1, ROR1);                       \
        s2 = ror_add(s2, ROR1); s3 = ror_add(s3, ROR1);                       \
        s0 = ror_add(s0, ROR2); s1 = ror_add(s1, ROR2);                       \
        s2 = ror_add(s2, ROR2); s3 = ror_add(s3, ROR2);                       \
        s0 = ror_add(s0, ROR4); s1 = ror_add(s1, ROR4);                       \
        s2 = ror_add(s2, ROR4); s3 = ror_add(s3, ROR4);                       \
        s0 = ror_add(s0, ROR8); s1 = ror_add(s1, ROR8);                       \
        s2 = ror_add(s2, ROR8); s3 = ror_add(s3, ROR8);                       \
        float4 h4;                                                            \
        h4.x = tanh_pade(s0 + xvf.x + bh4.x);                                 \
        h4.y = tanh_pade(s1 + xvf.y + bh4.y);                                 \
        h4.z = tanh_pade(s2 + xvf.z + bh4.z);                                 \
        h4.w = tanh_pade(s3 + xvf.w + bh4.w);                                 \
        if (p == 0)                                                           \
            *(float4*)&hbuf[(CUR) ^ 1][jg >> 1][(jg & 1) << 2] = h4;          \
        asm volatile("s_waitcnt lgkmcnt(0)" ::: "memory");                    \
        __builtin_amdgcn_s_barrier();                                         \
        asm volatile("" ::: "memory");                                        \
    } while (0)

    for (int t = 0; t < T_N; t += 2) {
        PSTEP(0);
        PSTEP(1);
    }
#undef PSTEP

    float4 hv0 = *(const float4*)&hbuf[0][p][0];
    if (tid == 0) ws[192 + blockIdx.x] = hv0.x;
}

extern "C" void kernel_launch(void* const* d_in, const int* in_sizes, int n_in,
                              void* d_out, int out_size, void* d_ws, size_t ws_size,
                              hipStream_t stream) {
    const float* x   = (const float*)d_in[0];
    const float* h0  = (const float*)d_in[1];
    const float* Wih = (const float*)d_in[2];
    const float* Whh = (const float*)d_in[3];
    const float* bih = (const float*)d_in[4];
    const float* bhh = (const float*)d_in[5];
    float* out = (float*)d_out;
    float* ws  = (float*)d_ws;

    xproj_kernel<<<dim3((T_N * B_N) / 128), 256, 0, stream>>>(x, Wih, bih, out);
    scan_kernel<<<dim3(B_N), 512, 0, stream>>>(Whh, bhh, h0, out);

    // --- probes (decomposition; write only to d_ws) ---
    probe_clock <<<dim3(B_N), 512, 0, stream>>>(ws);   // clock meter (argmax)
    probe_novmem<<<dim3(B_N), 512, 0, stream>>>(Whh, bhh, h0, ws);
}

// Round 9
// 1486.615 us; speedup vs baseline: 7.5412x; 7.5412x over previous
//
#include <hip/hip_runtime.h>

#define T_N 4096
#define B_N 64
#define I_N 128
#define H_N 128
#define BH  (B_N * H_N)

// ---------------------------------------------------------------------------
// Phase 1: xp = x @ W_ih^T + b_ih -> into out (in-place with phase 2).
// Unchanged from R2-R8 (~70 us).
// ---------------------------------------------------------------------------
__global__ __launch_bounds__(256) void xproj_kernel(
    const float* __restrict__ x, const float* __restrict__ Wih,
    const float* __restrict__ bih, float* __restrict__ xp)
{
    __shared__ float wt[I_N][H_N];   // wt[k][j] = Wih[j][k], 64 KB
    const int tid = threadIdx.x;

    {
        const float4* w4 = (const float4*)Wih;
        #pragma unroll
        for (int it = 0; it < 16; ++it) {
            int i = tid * 16 + it;          // 0..4095 float4s
            float4 v = w4[i];
            int r = i >> 5;                 // W row j
            int k = (i & 31) << 2;          // k base
            wt[k + 0][r] = v.x;
            wt[k + 1][r] = v.y;
            wt[k + 2][r] = v.z;
            wt[k + 3][r] = v.w;
        }
    }
    __syncthreads();

    const int  tx   = tid & 15;
    const int  ty   = tid >> 4;
    const long row0 = (long)blockIdx.x * 128;
    const float* xbase = x + (row0 + ty * 8) * I_N;

    float acc[8][8];
    #pragma unroll
    for (int r = 0; r < 8; ++r)
        #pragma unroll
        for (int c = 0; c < 8; ++c) acc[r][c] = 0.0f;

    #pragma unroll 2
    for (int k4 = 0; k4 < I_N / 4; ++k4) {
        float4 xv[8];
        #pragma unroll
        for (int r = 0; r < 8; ++r)
            xv[r] = *(const float4*)(xbase + r * I_N + k4 * 4);

        #pragma unroll
        for (int kk = 0; kk < 4; ++kk) {
            int k = k4 * 4 + kk;
            float4 w0 = *(const float4*)&wt[k][tx * 4];
            float4 w1 = *(const float4*)&wt[k][64 + tx * 4];
            #pragma unroll
            for (int r = 0; r < 8; ++r) {
                float xk = (kk == 0) ? xv[r].x : (kk == 1) ? xv[r].y
                         : (kk == 2) ? xv[r].z : xv[r].w;
                acc[r][0] = fmaf(xk, w0.x, acc[r][0]);
                acc[r][1] = fmaf(xk, w0.y, acc[r][1]);
                acc[r][2] = fmaf(xk, w0.z, acc[r][2]);
                acc[r][3] = fmaf(xk, w0.w, acc[r][3]);
                acc[r][4] = fmaf(xk, w1.x, acc[r][4]);
                acc[r][5] = fmaf(xk, w1.y, acc[r][5]);
                acc[r][6] = fmaf(xk, w1.z, acc[r][6]);
                acc[r][7] = fmaf(xk, w1.w, acc[r][7]);
            }
        }
    }

    float4 b0 = *(const float4*)(bih + tx * 4);
    float4 b1 = *(const float4*)(bih + 64 + tx * 4);
    #pragma unroll
    for (int r = 0; r < 8; ++r) {
        long row = row0 + ty * 8 + r;
        float4 o0, o1;
        o0.x = acc[r][0] + b0.x;  o0.y = acc[r][1] + b0.y;
        o0.z = acc[r][2] + b0.z;  o0.w = acc[r][3] + b0.w;
        o1.x = acc[r][4] + b1.x;  o1.y = acc[r][5] + b1.y;
        o1.z = acc[r][6] + b1.z;  o1.w = acc[r][7] + b1.w;
        *(float4*)(xp + row * H_N + tx * 4)      = o0;
        *(float4*)(xp + row * H_N + 64 + tx * 4) = o1;
    }
}

// ---------------------------------------------------------------------------
// Phase 2: scan, one block per batch (64 blocks x 512 threads).
// R9: ONE output per thread. Thread (p = lane&3 -> k-chunk [32p,32p+32),
// j = (lane>>2) + 16*wave). Per step/thread: 8 ds_read_b128 (conflict-free:
// hbuf[2][4][36], chunk bases at banks {0,4,8,12}), 8 parallel DOT4s +
// 3-level tree, 2 quad-perm DPP reduce rounds (vs 16 in R6), 1 tanh
// (exec-masked to p==0) -- measured VALU phase was 595 cyc of the 1037;
// this cuts its op count ~2.5x. Machinery (ds_write -> lgkmcnt(0) ->
// s_barrier -> ds_read, global store post-barrier) unchanged from R6.
// ---------------------------------------------------------------------------
__device__ __forceinline__ float tanh_pade(float x) {
    float u = x * x;
    float n = fmaf(u, u + 105.0f, 945.0f);              // u^2 + 105u + 945
    float d = fmaf(u, fmaf(15.0f, u, 420.0f), 945.0f);  // 15u^2 + 420u + 945
    float t = x * n * __builtin_amdgcn_rcpf(d);
    return fminf(1.0f, fmaxf(-1.0f, t));                // v_med3_f32
}

#define DPP_XOR1 0xB1   // quad_perm [1,0,3,2]
#define DPP_XOR2 0x4E   // quad_perm [2,3,0,1]

__device__ __forceinline__ float dpp_add(float v, const int ctrl) {
    int s = __float_as_int(v);
    int r;
    switch (ctrl) {  // ctrl must be a literal
        case DPP_XOR1: r = __builtin_amdgcn_update_dpp(0, s, DPP_XOR1, 0xF, 0xF, true); break;
        default:       r = __builtin_amdgcn_update_dpp(0, s, DPP_XOR2, 0xF, 0xF, true); break;
    }
    return v + __int_as_float(r);
}

#define DOT4(W4, H4)                                                          \
    fmaf((W4).x, (H4).x, fmaf((W4).y, (H4).y,                                 \
    fmaf((W4).z, (H4).z, (W4).w * (H4).w)))

__global__ __launch_bounds__(512, 1) void scan_kernel(
    const float* __restrict__ Whh, const float* __restrict__ bhh,
    const float* __restrict__ h0, float* __restrict__ out)
{
    const int tid  = threadIdx.x;
    const int b    = blockIdx.x;
    const int lane = tid & 63;
    const int wv   = tid >> 6;                 // 0..7
    const int p    = lane & 3;                 // k-chunk [32p, 32p+32)
    const int j    = (lane >> 2) + 16 * wv;    // output row 0..127
    __shared__ float hbuf[2][4][36];           // [buf][k-chunk][32 + 4 pad]

    // W fragment: w[c] = Whh[j][32p + 4c .. +4), 32 floats
    float4 w[8];
    #pragma unroll
    for (int c = 0; c < 8; ++c)
        w[c] = *(const float4*)(Whh + j * H_N + 32 * p + 4 * c);

    const float bh = bhh[j];

    if (tid < H_N) hbuf[0][tid >> 5][tid & 31] = h0[b * H_N + tid];

    const float* xq = out + b * H_N + j;   // xp (t,b,j) at xq + t*BH
    float*       oq = out + b * H_N + j;

    float xv[4];
    #pragma unroll
    for (int d = 0; d < 4; ++d)
        xv[d] = xq[(size_t)d * BH];

    __syncthreads();

#define RNN_STEP(T0, D, CUR) do {                                             \
        const float4* hb = (const float4*)&hbuf[CUR][p][0];                   \
        float4 hv0 = hb[0], hv1 = hb[1], hv2 = hb[2], hv3 = hb[3];            \
        float4 hv4 = hb[4], hv5 = hb[5], hv6 = hb[6], hv7 = hb[7];            \
        float d01 = DOT4(w[0], hv0) + DOT4(w[1], hv1);                        \
        float d23 = DOT4(w[2], hv2) + DOT4(w[3], hv3);                        \
        float d45 = DOT4(w[4], hv4) + DOT4(w[5], hv5);                        \
        float d67 = DOT4(w[6], hv6) + DOT4(w[7], hv7);                        \
        float s = (d01 + d23) + (d45 + d67);                                  \
        s = dpp_add(s, DPP_XOR1);                                             \
        s = dpp_add(s, DPP_XOR2);                                             \
        float hj;                                                             \
        if (p == 0) {                                                         \
            hj = tanh_pade(s + xv[D] + bh);                                   \
            hbuf[(CUR) ^ 1][j >> 5][j & 31] = hj;                             \
        }                                                                     \
        if ((T0) + 4 < T_N)                                                   \
            xv[D] = xq[(size_t)((T0) + 4) * BH];                              \
        asm volatile("s_waitcnt lgkmcnt(0)" ::: "memory");                    \
        __builtin_amdgcn_s_barrier();                                         \
        if (p == 0) {                                                         \
            oq[(size_t)(T0) * BH] = hj;                                       \
            if ((T0) == T_N - 1) oq[(size_t)T_N * BH] = hj;                   \
        }                                                                     \
        asm volatile("" ::: "memory");                                        \
    } while (0)

    for (int t = 0; t < T_N; t += 4) {
        RNN_STEP(t + 0, 0, 0);
        RNN_STEP(t + 1, 1, 1);
        RNN_STEP(t + 2, 2, 0);
        RNN_STEP(t + 3, 3, 1);
    }
#undef RNN_STEP
}

extern "C" void kernel_launch(void* const* d_in, const int* in_sizes, int n_in,
                              void* d_out, int out_size, void* d_ws, size_t ws_size,
                              hipStream_t stream) {
    const float* x   = (const float*)d_in[0];
    const float* h0  = (const float*)d_in[1];
    const float* Wih = (const float*)d_in[2];
    const float* Whh = (const float*)d_in[3];
    const float* bih = (const float*)d_in[4];
    const float* bhh = (const float*)d_in[5];
    float* out = (float*)d_out;

    xproj_kernel<<<dim3((T_N * B_N) / 128), 256, 0, stream>>>(x, Wih, bih, out);
    scan_kernel<<<dim3(B_N), 512, 0, stream>>>(Whh, bhh, h0, out);
}